// Round 16
// baseline (66.983 us; speedup 1.0000x reference)
//
#include <hip/hip_runtime.h>

// Local NCC loss on (2,1,160,160,160) f32, 5x5x5 box window, SAME zero pad.
// R16 = R15 with the DPP control as a TEMPLATE parameter (compile-time const,
// required by __builtin_amdgcn_update_dpp).
// LDS-FREE register-resident design. Lane <-> W column; wave = 64-lane
// W-tile (60 valid outputs) x 2 H rows x 8 D. Raw columns (6 rows x 2 vols)
// live in registers, loaded coalesced from global (L1/L2 serve the 3x H
// overlap; the 4 waves of a block are h-neighbors on one CU). Vertical 5-sums
// lane-local; W 5-window via symmetric DPP wave_shr:1/wave_shl:1 chains
// (VALU pipe — no LDS instructions at all, no barriers, no bank conflicts).
// D via the R8-verified compile-time phase guards (zs[5][5] x 2 rows = 50
// floats). Next-slab loads issued between the vertical sums (last raw readers)
// and the window/phase code for latency cover. launch_bounds(256,2): the
// proven no-spill codegen profile (~115 VGPR liveness).

#define DIM 160
#define SLAB (DIM * DIM)
#define VOL (DIM * DIM * DIM)
#define TD 8
#define NBLK 2400                 // 3 Wtiles x 20 hblocks x 20 dz x 2 batches
#define NPART (NBLK * 4)

template <int CTRL>
__device__ __forceinline__ float dppf(float x) {
    return __int_as_float(
        __builtin_amdgcn_update_dpp(0, __float_as_int(x), CTRL, 0xF, 0xF, true));
}

// symmetric 5-wide cross-lane window sum (lane <-> W column).
// wave_shr:1 (0x138) / wave_shl:1 (0x130); direction mix-up is harmless
// because the window is symmetric. Edge lanes get 0 (bound_ctrl) and their
// outputs are masked by om.
__device__ __forceinline__ float win5(float v) {
    const float p1 = dppf<0x138>(v);
    const float p2 = dppf<0x138>(p1);
    const float m1 = dppf<0x130>(v);
    const float m2 = dppf<0x130>(m1);
    return ((v + p1) + (p2 + m1)) + m2;
}

__global__ __launch_bounds__(256, 2)
void ncc_main(const float* __restrict__ real,
              const float* __restrict__ fake,
              float* __restrict__ partials) {
    const int tid  = threadIdx.x;
    const int lane = tid & 63;
    const int wid  = tid >> 6;

    // XCD-chunked swizzle (8 chunks of 300), dz fastest inside a chunk.
    const int bid = blockIdx.x;
    const int vid = (bid & 7) * 300 + (bid >> 3);
    const int dz  = vid % 20;
    const int hb  = (vid / 20) % 20;
    const int wt  = (vid / 400) % 3;
    const int nb  = vid / 1200;
    const int d0  = TD * dz;
    const int h0  = 2 * (hb * 4 + wid);      // wave-private h-pair
    const int c   = 60 * wt - 2 + lane;      // this lane's W column

    const float* bI = real + (size_t)nb * VOL;
    const float* bJ = fake + (size_t)nb * VOL;

    const int   ccl = min(max(c, 0), DIM - 1);
    const float wmf = ((unsigned)c < DIM) ? 1.f : 0.f;
    const float om  = (lane >= 2 && lane < 62 && c < DIM) ? 1.f : 0.f;

    int roff[6]; float mk[6];
#pragma unroll
    for (int r = 0; r < 6; ++r) {
        const int hr = h0 - 2 + r;
        mk[r]   = ((unsigned)hr < DIM) ? wmf : 0.f;
        roff[r] = min(max(hr, 0), DIM - 1) * DIM + ccl;
    }

    float aI[6], aJ[6];
    {   // prologue: slab s=0 (dd = d0-2); OOB -> zeros
        const int dd = d0 - 2;
        if ((unsigned)dd < DIM) {
            const int sb = dd * SLAB;
#pragma unroll
            for (int r = 0; r < 6; ++r) {
                aI[r] = bI[sb + roff[r]] * mk[r];
                aJ[r] = bJ[sb + roff[r]] * mk[r];
            }
        } else {
#pragma unroll
            for (int r = 0; r < 6; ++r) { aI[r] = 0.f; aJ[r] = 0.f; }
        }
    }

    float zs0[5][5], zs1[5][5];      // [phase][quantity] per h row, static only
#pragma unroll
    for (int p = 0; p < 5; ++p)
#pragma unroll
        for (int q = 0; q < 5; ++q) { zs0[p][q] = 0.f; zs1[p][q] = 0.f; }

    float acc = 0.f;
    const float inv = 1.0f / 125.0f;

#pragma unroll 1
    for (int a = 0; a < 3; ++a) {    // s = 5a+b, slabs 0..11
        const bool am0 = (a > 0);
#pragma unroll
        for (int b = 0; b < 5; ++b) {
            const bool compAct  = (a < 2) || (b < 2);   // s <= 11
            const bool stageAct = (a < 2) || (b == 0);  // s <= 10
            if (!compAct) continue;

            // ---- vertical 5-sums of {I,J,I2,J2,IJ} (last readers of aI/aJ) ----
            float s0[5], s1[5];
            {
                float q0v[5], q5v[5];
                q0v[0] = aI[0]; q0v[1] = aJ[0];
                q0v[2] = aI[0] * aI[0]; q0v[3] = aJ[0] * aJ[0]; q0v[4] = aI[0] * aJ[0];
                q5v[0] = aI[5]; q5v[1] = aJ[5];
                q5v[2] = aI[5] * aI[5]; q5v[3] = aJ[5] * aJ[5]; q5v[4] = aI[5] * aJ[5];
#pragma unroll
                for (int q = 0; q < 5; ++q) s0[q] = q0v[q];
#pragma unroll
                for (int r = 1; r < 5; ++r) {
                    s0[0] += aI[r]; s0[1] += aJ[r];
                    s0[2] += aI[r] * aI[r];
                    s0[3] += aJ[r] * aJ[r];
                    s0[4] += aI[r] * aJ[r];
                }
#pragma unroll
                for (int q = 0; q < 5; ++q) s1[q] = s0[q] - q0v[q] + q5v[q];
            }

            // ---- reload aI/aJ with next slab (overlaps window/phase code) ----
            if (stageAct) {
                const int dd1 = d0 - 1 + 5 * a + b;
                if ((unsigned)dd1 < DIM) {
                    const int sb = dd1 * SLAB;
#pragma unroll
                    for (int r = 0; r < 6; ++r) {
                        aI[r] = bI[sb + roff[r]] * mk[r];
                        aJ[r] = bJ[sb + roff[r]] * mk[r];
                    }
                } else {
#pragma unroll
                    for (int r = 0; r < 6; ++r) { aI[r] = 0.f; aJ[r] = 0.f; }
                }
            }

            // ---- cross-lane W 5-window via DPP ----
            float c0[5], c1[5];
#pragma unroll
            for (int q = 0; q < 5; ++q) { c0[q] = win5(s0[q]); c1[q] = win5(s1[q]); }

            // ---- add into active D-phases (guards uniform, indices static) ----
#pragma unroll
            for (int p = 0; p < 5; ++p) {
                const int kk  = (b - p + 5) % 5;   // compile-time
                const int bmk = b - kk;            // compile-time
                const bool doadd = (am0 || p <= b) &&
                                   (a == 0 || (a == 1 ? (bmk <= 2) : (bmk <= -3)));
                if (doadd) {
#pragma unroll
                    for (int q = 0; q < 5; ++q) { zs0[p][q] += c0[q]; zs1[p][q] += c1[q]; }
                }
            }

            // ---- completed output depth od = s-4 -> cc for 2 outputs ----
            const bool docomp = (a == 0) ? (b == 4) : ((a == 1) ? true : (b < 2));
            if (docomp) {
                const int pe = (b + 1) % 5;        // compile-time
                float cc2 = 0.f;
                {
                    const float SI = zs0[pe][0], SJ = zs0[pe][1];
                    const float S2I = zs0[pe][2], S2J = zs0[pe][3], SIJ = zs0[pe][4];
                    const float t0 = SI * inv;
                    const float cr = SIJ - t0 * SJ;
                    const float iv = S2I - t0 * SI;
                    const float jv = S2J - (SJ * inv) * SJ;
                    cc2 += cr * cr / (iv * jv + 1e-5f);
                }
                {
                    const float SI = zs1[pe][0], SJ = zs1[pe][1];
                    const float S2I = zs1[pe][2], S2J = zs1[pe][3], SIJ = zs1[pe][4];
                    const float t0 = SI * inv;
                    const float cr = SIJ - t0 * SJ;
                    const float iv = S2I - t0 * SI;
                    const float jv = S2J - (SJ * inv) * SJ;
                    cc2 += cr * cr / (iv * jv + 1e-5f);
                }
                acc += om * cc2;
#pragma unroll
                for (int q = 0; q < 5; ++q) { zs0[pe][q] = 0.f; zs1[pe][q] = 0.f; }
            }
        }
    }

    // ---- wave reduction -> one partial per wave ----
#pragma unroll
    for (int off = 32; off; off >>= 1)
        acc += __shfl_down(acc, off, 64);
    if (lane == 0)
        partials[bid * 4 + wid] = acc;
}

__global__ void ncc_reduce(const float* __restrict__ partials, float* __restrict__ out) {
    __shared__ double ws[4];
    double s = 0.0;
    for (int i = threadIdx.x; i < NPART; i += 256) s += (double)partials[i];
#pragma unroll
    for (int off = 32; off; off >>= 1)
        s += __shfl_down(s, off, 64);
    if ((threadIdx.x & 63) == 0) ws[threadIdx.x >> 6] = s;
    __syncthreads();
    if (threadIdx.x == 0) {
        const double t = ws[0] + ws[1] + ws[2] + ws[3];
        out[0] = (float)(t / (2.0 * (double)VOL));
    }
}

extern "C" void kernel_launch(void* const* d_in, const int* in_sizes, int n_in,
                              void* d_out, int out_size, void* d_ws, size_t ws_size,
                              hipStream_t stream) {
    const float* real = (const float*)d_in[0];
    const float* fake = (const float*)d_in[1];
    float* out      = (float*)d_out;
    float* partials = (float*)d_ws;   // NPART floats

    ncc_main<<<dim3(NBLK), dim3(256), 0, stream>>>(real, fake, partials);
    ncc_reduce<<<1, 256, 0, stream>>>(partials, out);
}